// Round 6
// baseline (9489.728 us; speedup 1.0000x reference)
//
#include <hip/hip_runtime.h>
#include <cstdint>
#include <cstddef>

// SimpleRNN on MI355X — round 8: round-4 tagged protocol + clock-paced sweeps.
//   h1_t = tanh(x_t Wih0^T + h2_{t-1} Whh0^T + bc0)      (L0 WGs)
//   h2_t = tanh(h1_t (Wih1+Whh1)^T + b1c)                 (L1 WGs)
//   y_t  = h2_t Wout^T + bout                             (L0 WGs waves 0-3)
// Protocol (round-4-proven): each h value travels as u32 = (f16<<16) | epoch.
// Consumer sweeps its 16 coalesced words and refetches stale ones until all
// carry the expected epoch. No flags, no drains, single buffer per direction
// (exact-epoch + dataflow ordering forbid overwrite-during-read).
// NEW: sweeps are clock-paced. Each consumer wave keeps next_ready/period in
// s_memrealtime ticks (100 MHz), waits on the CLOCK (no fabric traffic),
// issues one sweep timed to land just after producer stores become visible,
// and adapts: first-sweep-stale -> period += 16; clean -> period -= 2.
// Timing only affects performance, never correctness. All waits budget-bounded.

typedef _Float16 f16;
typedef _Float16 f16x8 __attribute__((ext_vector_type(8)));
typedef float    f32x4 __attribute__((ext_vector_type(4)));

#define NB 128
#define NT 1024
#define NI 256
#define NH 512
#define NO 256

#define WS_WHH0 (size_t)(0)        // 512*512 f16
#define WS_W1C  (size_t)(524288)   // 512*512 f16 (Wih1+Whh1)
#define WS_WOUT (size_t)(1048576)  // 256*512 f16
#define WS_WIH0 (size_t)(1310720)  // 512*256 f16
#define WS_BC0  (size_t)(1572864)  // 512 f32
#define WS_B1C  (size_t)(1574912)  // 512 f32
#define WS_BOUT (size_t)(1576960)  // 256 f32
#define WS_H1P  (size_t)(2097152)  // [8][16][512] u32 tagged h1 panel (256 KB)
#define WS_H2P  (size_t)(2621440)  // [8][16][512] u32 tagged h2 panel (256 KB)

#define AGENT __HIP_MEMORY_SCOPE_AGENT
#define SPIN_BUDGET (1 << 22)

__device__ __forceinline__ f32x4 mfma16(f16x8 a, f16x8 b, f32x4 c) {
  return __builtin_amdgcn_mfma_f32_16x16x32_f16(a, b, c, 0, 0, 0);
}

__device__ __forceinline__ float fast_tanh(float v) {
  float a = __builtin_fabsf(v);
  float e = __expf(-2.0f * a);                       // v_exp_f32
  float r = (1.0f - e) * __builtin_amdgcn_rcpf(1.0f + e);
  return v < 0.0f ? -r : r;
}

__device__ __forceinline__ uint32_t pack_h(float v, uint32_t tag) {
  union { f16 h; uint16_t u; } cv;
  cv.h = (f16)v;
  return ((uint32_t)cv.u << 16) | tag;
}

// Wait on the realtime clock until next_ready (no fabric traffic). Bounded.
__device__ __forceinline__ void wait_clock(uint64_t next_ready, int* budget) {
  for (;;) {
    uint64_t now = __builtin_amdgcn_s_memrealtime();
    if ((int64_t)(now - next_ready) >= 0) return;
    if (--(*budget) < 0) return;
    __builtin_amdgcn_s_sleep(1);
  }
}

// Check 16 previously-loaded words; refetch stale ones until all carry
// `expect`. Reports whether the FIRST check saw any stale word (pacing fb).
__device__ __forceinline__ void check_refetch16(uint32_t* __restrict__ panel,
                                                int tid, uint32_t expect,
                                                uint32_t w[16], int* budget,
                                                int* stale_first) {
  int first = 1;
  for (;;) {
    int stale = 0;
    #pragma unroll
    for (int i = 0; i < 16; i++)
      if ((w[i] & 0xFFFFu) != expect) stale |= (1 << i);
    if (first) { *stale_first = (stale != 0); first = 0; }
    if (!stale) return;
    if (--(*budget) < 0) return;   // hardening: terminate, don't hang
    #pragma unroll
    for (int i = 0; i < 16; i++)
      if (stale & (1 << i))
        w[i] = __hip_atomic_load(panel + tid + i * 512, __ATOMIC_RELAXED, AGENT);
  }
}

__global__ __launch_bounds__(256) void rnn9277_prep(
    const float* __restrict__ h0,
    const float* __restrict__ Wih0, const float* __restrict__ bih0,
    const float* __restrict__ Whh0, const float* __restrict__ bhh0,
    const float* __restrict__ Wih1, const float* __restrict__ bih1,
    const float* __restrict__ Whh1, const float* __restrict__ bhh1,
    const float* __restrict__ Woutp, const float* __restrict__ boutp,
    char* __restrict__ ws)
{
  const int tid = blockIdx.x * 256 + threadIdx.x;
  const int stride = gridDim.x * 256;
  f16* whh0 = (f16*)(ws + WS_WHH0);
  f16* w1c  = (f16*)(ws + WS_W1C);
  f16* wout = (f16*)(ws + WS_WOUT);
  f16* wih0 = (f16*)(ws + WS_WIH0);
  float* bc0 = (float*)(ws + WS_BC0);
  float* b1c = (float*)(ws + WS_B1C);
  float* bo  = (float*)(ws + WS_BOUT);
  uint32_t* h1p = (uint32_t*)(ws + WS_H1P);
  uint32_t* h2p = (uint32_t*)(ws + WS_H2P);

  for (int i = tid; i < NH * NH; i += stride) whh0[i] = (f16)Whh0[i];
  for (int i = tid; i < NH * NH; i += stride) w1c[i]  = (f16)(Wih1[i] + Whh1[i]);
  for (int i = tid; i < NO * NH; i += stride) wout[i] = (f16)Woutp[i];
  for (int i = tid; i < NH * NI; i += stride) wih0[i] = (f16)Wih0[i];
  for (int i = tid; i < NH; i += stride) { bc0[i] = bih0[i] + bhh0[i]; b1c[i] = bih1[i] + bhh1[i]; }
  for (int i = tid; i < NO; i += stride) bo[i] = boutp[i];

  // h1 panel: clear to tag 0 (valid h1 tags are 1..NT) — mandatory each launch
  // so stale tags from a previous run can never alias.
  for (int i = tid; i < 8 * 8192; i += stride)
    __hip_atomic_store(h1p + i, 0u, __ATOMIC_RELAXED, AGENT);
  // h0 -> h2 panel with tag 0 (L0 at t=0 expects tag 0).
  for (int i = tid; i < NB * NH; i += stride) {
    int b = i >> 9, c = i & 511;
    int g = b >> 4, r = b & 15;
    union { f16 h; uint16_t u; } cv;
    cv.h = (f16)h0[i];
    __hip_atomic_store(h2p + (size_t)g * 8192 + r * 512 + c,
                       (uint32_t)cv.u << 16, __ATOMIC_RELAXED, AGENT);
  }
}

__global__ __launch_bounds__(512) void rnn9277_chain(
    const float* __restrict__ x, float* __restrict__ out, char* __restrict__ ws)
{
  const int wg = blockIdx.x;                 // 0..63
  const bool isL0 = wg < 32;
  const int g = (wg & 31) >> 2, j = wg & 3;  // group, column-WG
  const int tid = threadIdx.x;               // 0..511
  const int wave = tid >> 6, lane = tid & 63;
  const int row16 = lane & 15, kq = lane >> 4;

  const f16* whh0 = (const f16*)(ws + WS_WHH0);
  const f16* w1c  = (const f16*)(ws + WS_W1C);
  const f16* wout = (const f16*)(ws + WS_WOUT);
  const f16* wih0 = (const f16*)(ws + WS_WIH0);
  const float* bc0 = (const float*)(ws + WS_BC0);
  const float* b1c = (const float*)(ws + WS_B1C);
  const float* bo  = (const float*)(ws + WS_BOUT);
  uint32_t* h1p = (uint32_t*)(ws + WS_H1P) + (size_t)g * 8192;
  uint32_t* h2p = (uint32_t*)(ws + WS_H2P) + (size_t)g * 8192;

  __shared__ __align__(16) f16 stage[2][16 * 520];   // staged h panel (padded)

  int budget = SPIN_BUDGET;

  // Pacing state (wave-uniform; 100 MHz realtime ticks: 1 tick ~= 24 sclk).
  uint64_t next_ready = 0;      // first sweeps immediate; adapts after
  int period = 120;             // ~4.8 us initial step-period guess
  const int P_MAX = 1500, P_UP = 16, P_DN = 2;

  // ---- Resident weight fragments ----
  f16x8 Bh[16];           // Whh0 (L0) or W1c (L1), 16 cols/wave
  f16x8 Bx[8];            // Wih0 (L0)
  f16x8 By[16];           // Wout (L0, waves 0..3)
  float bias = 0.f, ybias = 0.f;
  {
    const int col = j * 128 + wave * 16 + row16;
    const f16* wp = (isL0 ? whh0 : w1c) + (size_t)col * NH + kq * 8;
    #pragma unroll
    for (int kk = 0; kk < 16; kk++) Bh[kk] = *(const f16x8*)(wp + kk * 32);
    bias = (isL0 ? bc0 : b1c)[col];
    if (isL0) {
      const f16* qp = wih0 + (size_t)col * NI + kq * 8;
      #pragma unroll
      for (int kk = 0; kk < 8; kk++) Bx[kk] = *(const f16x8*)(qp + kk * 32);
      if (wave < 4) {
        const int oc = j * 64 + wave * 16 + row16;
        const f16* rp = wout + (size_t)oc * NH + kq * 8;
        #pragma unroll
        for (int kk = 0; kk < 16; kk++) By[kk] = *(const f16x8*)(rp + kk * 32);
        ybias = bo[oc];
      }
    }
  }

  if (isL0) {
    // ================= Layer-0 + output head =================
    for (int t = 0; t <= NT; ++t) {
      // Paced wait (clock only), then issue the sweep so it flies during x-part.
      wait_clock(next_ready, &budget);
      uint32_t w[16];
      #pragma unroll
      for (int i = 0; i < 16; i++)
        w[i] = __hip_atomic_load(h2p + tid + i * 512, __ATOMIC_RELAXED, AGENT);

      // x-part (recurrence-independent) hides the sweep latency.
      f32x4 accx = {0.f, 0.f, 0.f, 0.f};
      if (t < NT) {
        const float* xp = x + ((size_t)(g * 16 + row16) * NT + t) * NI + kq * 8;
        #pragma unroll
        for (int kk = 0; kk < 8; kk++) {
          f32x4 lo = *(const f32x4*)(xp + kk * 32);
          f32x4 hi = *(const f32x4*)(xp + kk * 32 + 4);
          f16x8 a;
          a[0] = (f16)lo[0]; a[1] = (f16)lo[1]; a[2] = (f16)lo[2]; a[3] = (f16)lo[3];
          a[4] = (f16)hi[0]; a[5] = (f16)hi[1]; a[6] = (f16)hi[2]; a[7] = (f16)hi[3];
          accx = mfma16(a, Bx[kk], accx);
        }
      }

      // Validate tags; refetch only stale words. Update pacing from feedback.
      int stale_first = 0;
      check_refetch16(h2p, tid, (uint32_t)t, w, &budget, &stale_first);
      {
        uint64_t done = __builtin_amdgcn_s_memrealtime();
        int st = __any(stale_first) ? 1 : 0;
        period = st ? (period + P_UP > P_MAX ? P_MAX : period + P_UP)
                    : (period - P_DN < 0 ? 0 : period - P_DN);
        next_ready = done + (uint64_t)period;
      }

      // Unpack straight into LDS stage (the sweep WAS the data load).
      f16* st16 = &stage[t & 1][0];
      #pragma unroll
      for (int i = 0; i < 16; i++) {
        union { uint16_t u; f16 h; } cv;
        cv.u = (uint16_t)(w[i] >> 16);
        st16[i * 520 + tid] = cv.h;
      }
      __syncthreads();   // the only barrier per iteration

      const f16* ap = st16 + row16 * 520 + kq * 8;
      if (t < NT) {
        // h-part: two interleaved accumulator chains.
        f32x4 acc2 = {0.f, 0.f, 0.f, 0.f};
        #pragma unroll
        for (int kk = 0; kk < 16; kk += 2) {
          accx = mfma16(*(const f16x8*)(ap + kk * 32), Bh[kk], accx);
          acc2 = mfma16(*(const f16x8*)(ap + (kk + 1) * 32), Bh[kk + 1], acc2);
        }
        // Publish h1_t directly from registers, tagged t+1. No drain, no flag.
        const int col = j * 128 + wave * 16 + row16;
        const uint32_t tag = (uint32_t)(t + 1);
        #pragma unroll
        for (int rr = 0; rr < 4; rr++) {
          uint32_t wv = pack_h(fast_tanh(accx[rr] + acc2[rr] + bias), tag);
          __hip_atomic_store(h1p + (kq * 4 + rr) * 512 + col, wv,
                             __ATOMIC_RELAXED, AGENT);
        }
      }
      // y_{t-1} = h2_{t-1} Wout^T + bout  (off critical path, after publish)
      if (t > 0 && wave < 4) {
        f32x4 ya = {0.f, 0.f, 0.f, 0.f};
        #pragma unroll
        for (int kk = 0; kk < 16; kk++)
          ya = mfma16(*(const f16x8*)(ap + kk * 32), By[kk], ya);
        const int oc = j * 64 + wave * 16 + row16;
        #pragma unroll
        for (int rr = 0; rr < 4; rr++)
          out[((size_t)(g * 16 + kq * 4 + rr) * NT + (t - 1)) * NO + oc] = ya[rr] + ybias;
      }
    }
  } else {
    // ================= Layer-1 =================
    for (int t = 0; t < NT; ++t) {
      wait_clock(next_ready, &budget);
      uint32_t w[16];
      #pragma unroll
      for (int i = 0; i < 16; i++)
        w[i] = __hip_atomic_load(h1p + tid + i * 512, __ATOMIC_RELAXED, AGENT);

      int stale_first = 0;
      check_refetch16(h1p, tid, (uint32_t)(t + 1), w, &budget, &stale_first);
      {
        uint64_t done = __builtin_amdgcn_s_memrealtime();
        int st = __any(stale_first) ? 1 : 0;
        period = st ? (period + P_UP > P_MAX ? P_MAX : period + P_UP)
                    : (period - P_DN < 0 ? 0 : period - P_DN);
        next_ready = done + (uint64_t)period;
      }

      f16* st16 = &stage[t & 1][0];
      #pragma unroll
      for (int i = 0; i < 16; i++) {
        union { uint16_t u; f16 h; } cv;
        cv.u = (uint16_t)(w[i] >> 16);
        st16[i * 520 + tid] = cv.h;
      }
      __syncthreads();

      const f16* ap = st16 + row16 * 520 + kq * 8;
      f32x4 a0 = {0.f, 0.f, 0.f, 0.f}, a1 = {0.f, 0.f, 0.f, 0.f};
      #pragma unroll
      for (int kk = 0; kk < 16; kk += 2) {
        a0 = mfma16(*(const f16x8*)(ap + kk * 32), Bh[kk], a0);
        a1 = mfma16(*(const f16x8*)(ap + (kk + 1) * 32), Bh[kk + 1], a1);
      }
      const int col = j * 128 + wave * 16 + row16;
      const uint32_t tag = (uint32_t)(t + 1);
      #pragma unroll
      for (int rr = 0; rr < 4; rr++) {
        uint32_t wv = pack_h(fast_tanh(a0[rr] + a1[rr] + bias), tag);
        __hip_atomic_store(h2p + (kq * 4 + rr) * 512 + col, wv,
                           __ATOMIC_RELAXED, AGENT);
      }
    }
  }
}

extern "C" void kernel_launch(void* const* d_in, const int* in_sizes, int n_in,
                              void* d_out, int out_size, void* d_ws, size_t ws_size,
                              hipStream_t stream) {
  const float* x    = (const float*)d_in[0];
  const float* h0   = (const float*)d_in[1];
  const float* Wih0 = (const float*)d_in[2];
  const float* bih0 = (const float*)d_in[3];
  const float* Whh0 = (const float*)d_in[4];
  const float* bhh0 = (const float*)d_in[5];
  const float* Wih1 = (const float*)d_in[6];
  const float* bih1 = (const float*)d_in[7];
  const float* Whh1 = (const float*)d_in[8];
  const float* bhh1 = (const float*)d_in[9];
  const float* Wout = (const float*)d_in[10];
  const float* bout = (const float*)d_in[11];
  char* ws = (char*)d_ws;
  float* out = (float*)d_out;

  rnn9277_prep<<<dim3(128), dim3(256), 0, stream>>>(
      h0, Wih0, bih0, Whh0, bhh0, Wih1, bih1, Whh1, bhh1, Wout, bout, ws);
  rnn9277_chain<<<dim3(64), dim3(512), 0, stream>>>(x, out, ws);
}

// Round 7
// 6893.459 us; speedup vs baseline: 1.3766x; 1.3766x over previous
//
#include <hip/hip_runtime.h>
#include <cstdint>
#include <cstddef>

// SimpleRNN on MI355X — round 9: round-2 protocol (proven fastest) with three
// critical-path trims. Protocol semantics UNCHANGED from the 6.10ms kernel:
// flags + producer drain + RD=4 ring, agent-scope relaxed atomics.
//   h1_t = tanh(x_t Wih0^T + h2_{t-1} Whh0^T + bc0)      (L0 WGs)
//   h2_t = tanh(h1_t (Wih1+Whh1)^T + b1c)                 (L1 WGs)
//   y_t  = h2_t Wout^T + bout                             (L0 WGs, off path)
// Trims:
//  (1) XOR-swizzled LDS stage (chunk ^= row&7): 8-way bank conflict on the
//      ds_read_b128 operand path -> 2-way (free). No padding needed.
//  (2) Direct-from-register ring publish (round-4-proven scatter): removes
//      the xpose LDS transpose + one barrier from the producer path.
//  (3) All waves poll the flags (uniform-addr loads broadcast): removes the
//      poll->stage barrier. 4 barriers/iter -> 2.

typedef _Float16 f16;
typedef _Float16 f16x8 __attribute__((ext_vector_type(8)));
typedef float    f32x4 __attribute__((ext_vector_type(4)));

#define NB 128
#define NT 1024
#define NI 256
#define NH 512
#define NO 256
#define RD 4

#define WS_WHH0 (size_t)(0)        // 512*512 f16
#define WS_W1C  (size_t)(524288)   // 512*512 f16 (Wih1+Whh1)
#define WS_WOUT (size_t)(1048576)  // 256*512 f16
#define WS_WIH0 (size_t)(1310720)  // 512*256 f16
#define WS_BC0  (size_t)(1572864)  // 512 f32
#define WS_B1C  (size_t)(1574912)  // 512 f32
#define WS_BOUT (size_t)(1576960)  // 256 f32
#define WS_H1R  (size_t)(2097152)  // [8][4][16][512] f16
#define WS_H2R  (size_t)(2621440)  // [8][4][16][512] f16
#define WS_FLG  (size_t)(3145728)  // h1 flags 32@64B; h2 flags at +2048

#define AGENT __HIP_MEMORY_SCOPE_AGENT
#define SPIN_BUDGET (1 << 22)

__device__ __forceinline__ f32x4 mfma16(f16x8 a, f16x8 b, f32x4 c) {
  return __builtin_amdgcn_mfma_f32_16x16x32_f16(a, b, c, 0, 0, 0);
}

__device__ __forceinline__ float fast_tanh(float v) {
  float a = __builtin_fabsf(v);
  float e = __expf(-2.0f * a);                       // v_exp_f32
  float r = (1.0f - e) * __builtin_amdgcn_rcpf(1.0f + e);
  return v < 0.0f ? -r : r;
}

__device__ __forceinline__ void drain_vm() {
  asm volatile("s_waitcnt vmcnt(0)" ::: "memory");
}

// Poll 4 per-WG flags (64B apart) until all >= target. Run by ALL threads
// (uniform addresses broadcast -> cheap). Budget-bounded, never hangs.
__device__ __forceinline__ void poll4(int* base, int target, int* budget) {
  for (;;) {
    int a = __hip_atomic_load(base,      __ATOMIC_RELAXED, AGENT);
    int b = __hip_atomic_load(base + 16, __ATOMIC_RELAXED, AGENT);
    int c = __hip_atomic_load(base + 32, __ATOMIC_RELAXED, AGENT);
    int d = __hip_atomic_load(base + 48, __ATOMIC_RELAXED, AGENT);
    if (a >= target && b >= target && c >= target && d >= target) break;
    if (--(*budget) < 0) break;    // hardening: terminate, don't hang
    __builtin_amdgcn_s_sleep(1);
  }
  asm volatile("" ::: "memory");   // stage loads must not be hoisted above poll
}

// Stage the 16x512 f16 panel into LDS with XOR swizzle: 16B chunk index
// within a row is XORed with (row&7). Row stride 512 f16 (1KB), no pad.
// Makes the MFMA ds_read_b128 pattern 2-way (free) instead of 8-way.
__device__ __forceinline__ void stage_sw(const uint64_t* rs, int tid, f16* st) {
  #pragma unroll
  for (int i = 0; i < 4; ++i) {
    int cc = tid + i * 512;
    int r = cc >> 7, c4 = cc & 127;          // row, u64-col
    uint64_t v = __hip_atomic_load(rs + cc, __ATOMIC_RELAXED, AGENT);
    int f = r * 512 + (((c4 >> 1) ^ (r & 7)) << 3) + ((c4 & 1) << 2);
    *(uint64_t*)(st + f) = v;
  }
}

__global__ __launch_bounds__(256) void rnn9277_prep(
    const float* __restrict__ h0,
    const float* __restrict__ Wih0, const float* __restrict__ bih0,
    const float* __restrict__ Whh0, const float* __restrict__ bhh0,
    const float* __restrict__ Wih1, const float* __restrict__ bih1,
    const float* __restrict__ Whh1, const float* __restrict__ bhh1,
    const float* __restrict__ Woutp, const float* __restrict__ boutp,
    char* __restrict__ ws)
{
  const int tid = blockIdx.x * 256 + threadIdx.x;
  const int stride = gridDim.x * 256;
  f16* whh0 = (f16*)(ws + WS_WHH0);
  f16* w1c  = (f16*)(ws + WS_W1C);
  f16* wout = (f16*)(ws + WS_WOUT);
  f16* wih0 = (f16*)(ws + WS_WIH0);
  float* bc0 = (float*)(ws + WS_BC0);
  float* b1c = (float*)(ws + WS_B1C);
  float* bo  = (float*)(ws + WS_BOUT);
  uint64_t* h2r64 = (uint64_t*)(ws + WS_H2R);
  int* h1f = (int*)(ws + WS_FLG);
  int* h2f = (int*)(ws + WS_FLG + 2048);

  for (int i = tid; i < NH * NH; i += stride) whh0[i] = (f16)Whh0[i];
  for (int i = tid; i < NH * NH; i += stride) w1c[i]  = (f16)(Wih1[i] + Whh1[i]);
  for (int i = tid; i < NO * NH; i += stride) wout[i] = (f16)Woutp[i];
  for (int i = tid; i < NH * NI; i += stride) wih0[i] = (f16)Wih0[i];
  for (int i = tid; i < NH; i += stride) { bc0[i] = bih0[i] + bhh0[i]; b1c[i] = bih1[i] + bhh1[i]; }
  for (int i = tid; i < NO; i += stride) bo[i] = boutp[i];
  // h0 -> h2 ring slot 3 (t = -1), agent-scope 8B stores.
  for (int c = tid; c < NB * NH / 4; c += stride) {
    int b = c >> 7, c4 = c & 127;
    int g = b >> 4, bl = b & 15;
    const float* hp = h0 + (size_t)b * NH + c4 * 4;
    union { uint64_t u; f16 h[4]; } uv;
    uv.h[0] = (f16)hp[0]; uv.h[1] = (f16)hp[1]; uv.h[2] = (f16)hp[2]; uv.h[3] = (f16)hp[3];
    __hip_atomic_store(h2r64 + (size_t)(g * RD + 3) * 2048 + bl * 128 + c4, uv.u,
                       __ATOMIC_RELAXED, AGENT);
  }
  if (tid < 32) {
    __hip_atomic_store(h1f + tid * 16, 0, __ATOMIC_RELAXED, AGENT);
    __hip_atomic_store(h2f + tid * 16, 0, __ATOMIC_RELAXED, AGENT);
  }
}

__global__ __launch_bounds__(512) void rnn9277_chain(
    const float* __restrict__ x, float* __restrict__ out, char* __restrict__ ws)
{
  const int wg = blockIdx.x;                 // 0..63
  const bool isL0 = wg < 32;
  const int g = (wg & 31) >> 2, j = wg & 3;  // group, column-WG
  const int tid = threadIdx.x;               // 0..511
  const int wave = tid >> 6, lane = tid & 63;
  const int row16 = lane & 15, kq = lane >> 4;
  const int khi = (row16 >> 2) & 1;          // swizzle bit for kk
  const int kql = (kq ^ (row16 & 3)) << 3;   // swizzled kq offset (f16 units)

  const f16* whh0 = (const f16*)(ws + WS_WHH0);
  const f16* w1c  = (const f16*)(ws + WS_W1C);
  const f16* wout = (const f16*)(ws + WS_WOUT);
  const f16* wih0 = (const f16*)(ws + WS_WIH0);
  const float* bc0 = (const float*)(ws + WS_BC0);
  const float* b1c = (const float*)(ws + WS_B1C);
  const float* bo  = (const float*)(ws + WS_BOUT);
  uint64_t* h1r64 = (uint64_t*)(ws + WS_H1R);
  uint64_t* h2r64 = (uint64_t*)(ws + WS_H2R);
  int* h1fb = (int*)(ws + WS_FLG) + g * 64;          // 4 flags, 64B apart
  int* h2fb = (int*)(ws + WS_FLG + 2048) + g * 64;

  __shared__ __align__(16) f16 stage[2][16 * 512];   // swizzled stage (32 KB)

  int budget = SPIN_BUDGET;

  // ---- Resident weight fragments ----
  f16x8 Bh[16];           // Whh0 (L0) or W1c (L1), 16 cols/wave
  f16x8 Bx[8];            // Wih0 (L0)
  f16x8 By[16];           // Wout (L0, waves 0..3)
  float bias = 0.f, ybias = 0.f;
  {
    const int col = j * 128 + wave * 16 + row16;
    const f16* wp = (isL0 ? whh0 : w1c) + (size_t)col * NH + kq * 8;
    #pragma unroll
    for (int kk = 0; kk < 16; kk++) Bh[kk] = *(const f16x8*)(wp + kk * 32);
    bias = (isL0 ? bc0 : b1c)[col];
    if (isL0) {
      const f16* qp = wih0 + (size_t)col * NI + kq * 8;
      #pragma unroll
      for (int kk = 0; kk < 8; kk++) Bx[kk] = *(const f16x8*)(qp + kk * 32);
      if (wave < 4) {
        const int oc = j * 64 + wave * 16 + row16;
        const f16* rp = wout + (size_t)oc * NH + kq * 8;
        #pragma unroll
        for (int kk = 0; kk < 16; kk++) By[kk] = *(const f16x8*)(rp + kk * 32);
        ybias = bo[oc];
      }
    }
  }

  if (isL0) {
    // ================= Layer-0 + output head =================
    for (int t = 0; t <= NT; ++t) {
      // x-part (recurrence-independent, before poll)
      f32x4 accx = {0.f, 0.f, 0.f, 0.f};
      if (t < NT) {
        const float* xp = x + ((size_t)(g * 16 + row16) * NT + t) * NI + kq * 8;
        #pragma unroll
        for (int kk = 0; kk < 8; kk++) {
          f32x4 lo = *(const f32x4*)(xp + kk * 32);
          f32x4 hi = *(const f32x4*)(xp + kk * 32 + 4);
          f16x8 a;
          a[0] = (f16)lo[0]; a[1] = (f16)lo[1]; a[2] = (f16)lo[2]; a[3] = (f16)lo[3];
          a[4] = (f16)hi[0]; a[5] = (f16)hi[1]; a[6] = (f16)hi[2]; a[7] = (f16)hi[3];
          accx = mfma16(a, Bx[kk], accx);
        }
      }
      // all waves poll h2_{t-1}; no broadcast barrier needed
      poll4(h2fb, t, &budget);
      stage_sw(h2r64 + (size_t)(g * RD + ((t + 3) & 3)) * 2048, tid, &stage[t & 1][0]);
      __syncthreads();

      const f16* ap = &stage[t & 1][0] + row16 * 512 + kql;
      if (t < NT) {
        // h-part: two interleaved accumulator chains, swizzled reads
        f32x4 acc2 = {0.f, 0.f, 0.f, 0.f};
        #pragma unroll
        for (int kk = 0; kk < 16; kk += 2) {
          accx = mfma16(*(const f16x8*)(ap + ((kk ^ khi) << 5)),       Bh[kk],     accx);
          acc2 = mfma16(*(const f16x8*)(ap + (((kk + 1) ^ khi) << 5)), Bh[kk + 1], acc2);
        }
        // direct-from-register publish (no xpose): 4 f16 scatter per thread
        uint16_t* pan = (uint16_t*)(h1r64 + (size_t)(g * RD + (t & 3)) * 2048);
        const int col = j * 128 + wave * 16 + row16;
        #pragma unroll
        for (int rr = 0; rr < 4; rr++) {
          union { f16 h; uint16_t u; } cv;
          cv.h = (f16)fast_tanh(accx[rr] + acc2[rr] + bias);
          __hip_atomic_store(pan + (kq * 4 + rr) * 512 + col, cv.u,
                             __ATOMIC_RELAXED, AGENT);
        }
        drain_vm();        // per-wave: data stores acked before barrier
        __syncthreads();   // all waves' stores acked before flag
        if (tid == 0)
          __hip_atomic_store(h1fb + j * 16, t + 1, __ATOMIC_RELAXED, AGENT);
      }
      // y_{t-1} = h2_{t-1} Wout^T + bout  (off critical path, after flag)
      if (t > 0 && wave < 4) {
        f32x4 ya = {0.f, 0.f, 0.f, 0.f};
        #pragma unroll
        for (int kk = 0; kk < 16; kk++)
          ya = mfma16(*(const f16x8*)(ap + ((kk ^ khi) << 5)), By[kk], ya);
        const int oc = j * 64 + wave * 16 + row16;
        #pragma unroll
        for (int rr = 0; rr < 4; rr++)
          out[((size_t)(g * 16 + kq * 4 + rr) * NT + (t - 1)) * NO + oc] = ya[rr] + ybias;
      }
    }
  } else {
    // ================= Layer-1 =================
    for (int t = 0; t < NT; ++t) {
      poll4(h1fb, t + 1, &budget);
      stage_sw(h1r64 + (size_t)(g * RD + (t & 3)) * 2048, tid, &stage[t & 1][0]);
      __syncthreads();

      const f16* ap = &stage[t & 1][0] + row16 * 512 + kql;
      f32x4 a0 = {0.f, 0.f, 0.f, 0.f}, a1 = {0.f, 0.f, 0.f, 0.f};
      #pragma unroll
      for (int kk = 0; kk < 16; kk += 2) {
        a0 = mfma16(*(const f16x8*)(ap + ((kk ^ khi) << 5)),       Bh[kk],     a0);
        a1 = mfma16(*(const f16x8*)(ap + (((kk + 1) ^ khi) << 5)), Bh[kk + 1], a1);
      }
      uint16_t* pan = (uint16_t*)(h2r64 + (size_t)(g * RD + (t & 3)) * 2048);
      const int col = j * 128 + wave * 16 + row16;
      #pragma unroll
      for (int rr = 0; rr < 4; rr++) {
        union { f16 h; uint16_t u; } cv;
        cv.h = (f16)fast_tanh(a0[rr] + a1[rr] + bias);
        __hip_atomic_store(pan + (kq * 4 + rr) * 512 + col, cv.u,
                           __ATOMIC_RELAXED, AGENT);
      }
      drain_vm();
      __syncthreads();
      if (tid == 0)
        __hip_atomic_store(h2fb + j * 16, t + 1, __ATOMIC_RELAXED, AGENT);
    }
  }
}

extern "C" void kernel_launch(void* const* d_in, const int* in_sizes, int n_in,
                              void* d_out, int out_size, void* d_ws, size_t ws_size,
                              hipStream_t stream) {
  const float* x    = (const float*)d_in[0];
  const float* h0   = (const float*)d_in[1];
  const float* Wih0 = (const float*)d_in[2];
  const float* bih0 = (const float*)d_in[3];
  const float* Whh0 = (const float*)d_in[4];
  const float* bhh0 = (const float*)d_in[5];
  const float* Wih1 = (const float*)d_in[6];
  const float* bih1 = (const float*)d_in[7];
  const float* Whh1 = (const float*)d_in[8];
  const float* bhh1 = (const float*)d_in[9];
  const float* Wout = (const float*)d_in[10];
  const float* bout = (const float*)d_in[11];
  char* ws = (char*)d_ws;
  float* out = (float*)d_out;

  rnn9277_prep<<<dim3(128), dim3(256), 0, stream>>>(
      h0, Wih0, bih0, Whh0, bhh0, Wih1, bih1, Whh1, bhh1, Wout, bout, ws);
  rnn9277_chain<<<dim3(64), dim3(512), 0, stream>>>(x, out, ws);
}